// Round 11
// baseline (925.000 us; speedup 1.0000x reference)
//
#include <hip/hip_runtime.h>

#define NSITES 64
#define CHI 64
#define BATCH 32768
#define LPAD 66          // L row stride in doubles

typedef double d4 __attribute__((ext_vector_type(4)));

// 32 cycles of guaranteed spacing between MFMA result writes and VALU reads,
// pinned so the compiler cannot move register-only MFMAs across (rule #18).
#define MFMA_HAZARD_FENCE() do {                                    \
    __builtin_amdgcn_sched_barrier(0);                              \
    asm volatile("s_nop 7\n\ts_nop 7\n\ts_nop 7\n\ts_nop 7" :::);   \
    __builtin_amdgcn_sched_barrier(0);                              \
} while (0)

// ============================================================================
// Kernel 1: per-site Householder QR (LAPACK dgeqrf/dorgqr convention), f64.
// REWRITTEN for barrier economy (same math, ulp-level regrouping only):
//  - factor: 2 barriers/iter (was 4): u cached in regs during GEMV phase
//    (update never re-reads col k -> col-k scaling runs inside update phase);
//    next column-norm partials computed by the jf==k+1 threads right after
//    they update that column (redS2), consumed after the end barrier.
//  - Q-phase: scaled v's transposed once into padded Vt[64][136]
//    (idx rr+(rr>>4): conflict-free octant reads), then 64 iters with ZERO
//    barriers (Vt read-only).
// Output unchanged: A8[i*8192 + l*128 + sr] = Q[sr][l].
// ============================================================================
__global__ __launch_bounds__(512) void qr_site_kernel(
    const float* __restrict__ W, double* __restrict__ A8)
{
    __shared__ double M[128][65];
    __shared__ double wpart[8][64];
    __shared__ double tauS[64];
    __shared__ double redS2[8];
    __shared__ double Vt[64][136];

    const int i   = blockIdx.x;
    const int tid = threadIdx.x;

    for (int idx = tid; idx < 8192; idx += 512) {
        int l = idx >> 7, sr = idx & 127;
        M[sr][l] = (double)W[i * 8192 + idx];
    }

    const int jf = tid & 63;              // column
    const int gf = tid >> 6;              // row group 0..7 (rows gf*16..+16)
    const int r0 = gf * 16;
    __syncthreads();

    // pre-loop: column-0 norm partials over rows 1..127
    if (jf == 0) {
        double s = 0.0;
        #pragma unroll 4
        for (int m = 0; m < 16; ++m) {
            int rr = r0 + m;
            double x = (rr >= 1) ? M[rr][0] : 0.0;
            s = fma(x, x, s);
        }
        redS2[gf] = s;
    }
    __syncthreads();

    for (int k = 0; k < 64; ++k) {
        // scalars: identical IEEE ops on all threads -> deterministic
        const double v2 = ((redS2[0] + redS2[1]) + (redS2[2] + redS2[3]))
                        + ((redS2[4] + redS2[5]) + (redS2[6] + redS2[7]));
        const double alpha = M[k][k];
        double beta, tk;
        if (v2 == 0.0) { beta = alpha; tk = 0.0; }
        else {
            double nrm = sqrt(alpha * alpha + v2);
            beta = (alpha >= 0.0) ? -nrm : nrm;
            tk   = (beta - alpha) / beta;
        }
        const double uk   = alpha - beta;
        const double sc   = (tk != 0.0) ? (1.0 / uk) : 0.0;
        const double tau2 = (tk != 0.0) ? (tk / (uk * uk)) : 0.0;
        if (tid == 0) tauS[k] = tk;

        // cache unscaled u for own rows (reads of col k all happen pre-barrier)
        double ureg[16];
        #pragma unroll 4
        for (int m = 0; m < 16; ++m) {
            int rr = r0 + m;
            ureg[m] = (rr > k) ? M[rr][k] : ((rr == k) ? uk : 0.0);
        }
        double part = 0.0;
        if (jf > k) {
            #pragma unroll 4
            for (int m = 0; m < 16; ++m)
                part = fma(ureg[m], M[r0 + m][jf], part);
        }
        wpart[gf][jf] = part;
        __syncthreads();                  // barrier 1: GEMV partials ready

        if (jf > k) {
            double wj = tau2 * (((wpart[0][jf] + wpart[1][jf]) + (wpart[2][jf] + wpart[3][jf]))
                              + ((wpart[4][jf] + wpart[5][jf]) + (wpart[6][jf] + wpart[7][jf])));
            if (jf == k + 1) {            // update col k+1 AND its norm partial
                double s = 0.0;
                #pragma unroll 4
                for (int m = 0; m < 16; ++m) {
                    int rr = r0 + m;
                    double nv = fma(-ureg[m], wj, M[rr][jf]);
                    M[rr][jf] = nv;
                    if (rr > k + 1) s = fma(nv, nv, s);
                }
                redS2[gf] = s;
            } else {
                #pragma unroll 4
                for (int m = 0; m < 16; ++m) {
                    int rr = r0 + m;
                    M[rr][jf] = fma(-ureg[m], wj, M[rr][jf]);
                }
            }
        } else if (jf == k) {
            // scale col k -> stored v (no remaining readers of col k this iter)
            #pragma unroll 4
            for (int m = 0; m < 16; ++m) {
                int rr = r0 + m;
                if (rr > k) M[rr][k] = ureg[m] * sc;
            }
        }
        __syncthreads();                  // barrier 2: updates + norm ready
    }

    // transpose scaled v's into Vt (v_k = 1 implicit -> explicit here)
    for (int idx = tid; idx < 8192; idx += 512) {
        int rr = idx & 127, k = idx >> 7;
        double val = (rr > k) ? M[rr][k] : ((rr == k) ? 1.0 : 0.0);
        Vt[k][rr + (rr >> 4)] = val;
    }
    __syncthreads();

    // Q = H_0 ... H_63 applied to [I;0], reverse order — ZERO barriers
    const int jq = tid >> 3;              // column 0..63
    const int qq = tid & 7;               // row octant
    double E[16];
    #pragma unroll
    for (int m = 0; m < 16; ++m) E[m] = ((qq * 16 + m) == jq) ? 1.0 : 0.0;

    for (int k = 63; k >= 0; --k) {
        const double tkk = tauS[k];
        double part = 0.0;
        #pragma unroll
        for (int m = 0; m < 16; ++m) {
            int rr = qq * 16 + m;
            part = fma(Vt[k][rr + qq], E[m], part);
        }
        part += __shfl_xor(part, 1, 64);
        part += __shfl_xor(part, 2, 64);
        part += __shfl_xor(part, 4, 64);
        const double wj = tkk * part;
        #pragma unroll
        for (int m = 0; m < 16; ++m) {
            int rr = qq * 16 + m;
            E[m] = fma(-Vt[k][rr + qq], wj, E[m]);
        }
    }

    double* dst = A8 + (size_t)i * 8192 + jq * 128 + qq * 16;
    #pragma unroll
    for (int m = 0; m < 16; ++m) dst[m] = E[m];
}

// ============================================================================
// Kernel 2: sampling via f64 MFMA GEMM per site. CHANGE vs round 10:
// zero-serial staging schedule —
//   issue nxH0 | MFMA kk0..7 (H0) | BAR_A | ds_write H0 + issue nxH1 |
//   MFMA kk8..15 (H1) | fence | epilogue+L+outputs | BAR_B | ds_write H1
// All ds_writes overlap MFMA or next-site front; serial region = 2 barriers.
// ============================================================================
#define MFMA_ROW(bp, a)                                                   \
    c0 = __builtin_amdgcn_mfma_f64_16x16x4f64((a), (bp)[  0], c0, 0,0,0); \
    c1 = __builtin_amdgcn_mfma_f64_16x16x4f64((a), (bp)[ 16], c1, 0,0,0); \
    c2 = __builtin_amdgcn_mfma_f64_16x16x4f64((a), (bp)[ 32], c2, 0,0,0); \
    c3 = __builtin_amdgcn_mfma_f64_16x16x4f64((a), (bp)[ 48], c3, 0,0,0); \
    c4 = __builtin_amdgcn_mfma_f64_16x16x4f64((a), (bp)[ 64], c4, 0,0,0); \
    c5 = __builtin_amdgcn_mfma_f64_16x16x4f64((a), (bp)[ 80], c5, 0,0,0); \
    c6 = __builtin_amdgcn_mfma_f64_16x16x4f64((a), (bp)[ 96], c6, 0,0,0); \
    c7 = __builtin_amdgcn_mfma_f64_16x16x4f64((a), (bp)[112], c7, 0,0,0);

__global__ __launch_bounds__(512, 2) void sample_kernel(
    const double* __restrict__ A8, const float* __restrict__ u,
    float* __restrict__ out)
{
    __shared__ __align__(16) double As[8192];        // A_i: [j=64][sr=128], 64 KiB
    __shared__ double Lsm[128 * LPAD];               // L: [b=128][j=64 + pad], 66 KiB

    const int tid  = threadIdx.x;
    const int w    = tid >> 6;            // wave 0..7
    const int lane = tid & 63;
    const int g    = lane >> 4;           // 0..3
    const int r    = lane & 15;           // 0..15
    const int ubase = blockIdx.x * 128 + 16 * w;   // strip's first global batch

    // ---- layout probe (register-only, once) ----
    d4 zp = {0.0, 0.0, 0.0, 0.0};
    const d4 rowP = __builtin_amdgcn_mfma_f64_16x16x4f64((g == 0) ? (double)r : 0.0, 1.0, zp, 0, 0, 0);
    const d4 colP = __builtin_amdgcn_mfma_f64_16x16x4f64((g == 0) ? 1.0 : 0.0, (double)r, zp, 0, 0, 0);
    MFMA_HAZARD_FENCE();
    const int row0 = (int)(rowP.x + 0.5), row1 = (int)(rowP.y + 0.5);
    const int row2 = (int)(rowP.z + 0.5), row3 = (int)(rowP.w + 0.5);
    const int col0 = (int)(colP.x + 0.5), col1 = (int)(colP.y + 0.5);
    const int col2 = (int)(colP.z + 0.5), col3 = (int)(colP.w + 0.5);

    // init L = e_0: lane (g,r) initializes row 16w+r, cols g, g+4, ...
    for (int j = g; j < 64; j += 4)
        Lsm[(16 * w + r) * LPAD + j] = (j == 0) ? 1.0 : 0.0;

    {   // stage site 0 (full)
        const double2* s2 = (const double2*)A8;
        double2* a2 = (double2*)As;
        #pragma unroll
        for (int q = 0; q < 8; ++q) a2[q * 512 + tid] = s2[q * 512 + tid];
    }
    __syncthreads();

    float* probOut = out + (size_t)BATCH * (NSITES * 2);

    for (int site = 0; site < NSITES; ++site) {
        // u values for this lane's (probed) batch rows
        const float u0 = u[(size_t)(ubase + row0) * NSITES + site];
        const float u1 = u[(size_t)(ubase + row1) * NSITES + site];
        const float u2 = u[(size_t)(ubase + row2) * NSITES + site];
        const float u3 = u[(size_t)(ubase + row3) * NSITES + site];

        // issue next-site H0 loads (arrive under first MFMA half)
        double2 st0, st1, st2, st3;
        if (site < NSITES - 1) {
            const double2* nx = (const double2*)(A8 + (size_t)(site + 1) * 8192);
            st0 = nx[0 * 512 + tid]; st1 = nx[1 * 512 + tid];
            st2 = nx[2 * 512 + tid]; st3 = nx[3 * 512 + tid];
        }

        d4 c0 = {0.0, 0.0, 0.0, 0.0}, c1 = c0, c2 = c0, c3 = c0;
        d4 c4 = c0, c5 = c0, c6 = c0, c7 = c0;

        const double* Lp = Lsm + (16 * w + r) * LPAD + g;   // A-op: L[16w+r][g+4kk]
        const double* Ap = As + g * 128 + r;                // B-op: A[g+4kk][16t+r]

        // ---- first half: kk 0..7 (reads As rows 0..31 = H0) ----
        #pragma unroll
        for (int kk = 0; kk < 8; ++kk) {
            const double a = Lp[4 * kk];
            const double* bp = Ap + kk * 512;
            MFMA_ROW(bp, a)
        }

        __syncthreads();                 // BAR_A: all H0 reads done

        // overwrite H0 + issue H1 loads; both overlap the second MFMA half
        double2 st4, st5, st6, st7;
        if (site < NSITES - 1) {
            double2* a2 = (double2*)As;
            a2[0 * 512 + tid] = st0; a2[1 * 512 + tid] = st1;
            a2[2 * 512 + tid] = st2; a2[3 * 512 + tid] = st3;
            const double2* nx = (const double2*)(A8 + (size_t)(site + 1) * 8192);
            st4 = nx[4 * 512 + tid]; st5 = nx[5 * 512 + tid];
            st6 = nx[6 * 512 + tid]; st7 = nx[7 * 512 + tid];
        }

        // ---- second half: kk 8..15 (reads As rows 32..63 = H1) ----
        #pragma unroll
        for (int kk = 8; kk < 16; ++kk) {
            const double a = Lp[4 * kk];
            const double* bp = Ap + kk * 512;
            MFMA_ROW(bp, a)
        }
        MFMA_HAZARD_FENCE();             // settle all c-reg writes before VALU reads

        // p0 per row: tiles 0..3 are the s=0 half (col-permutation-invariant);
        // xor-butterfly over the 16-lane group (row map is r-independent).
        double P0 = fma(c3.x, c3.x, fma(c2.x, c2.x, fma(c1.x, c1.x, c0.x * c0.x)));
        double P1 = fma(c3.y, c3.y, fma(c2.y, c2.y, fma(c1.y, c1.y, c0.y * c0.y)));
        double P2 = fma(c3.z, c3.z, fma(c2.z, c2.z, fma(c1.z, c1.z, c0.z * c0.z)));
        double P3 = fma(c3.w, c3.w, fma(c2.w, c2.w, fma(c1.w, c1.w, c0.w * c0.w)));
        #pragma unroll
        for (int m = 1; m <= 8; m <<= 1) {
            P0 += __shfl_xor(P0, m, 64);
            P1 += __shfl_xor(P1, m, 64);
            P2 += __shfl_xor(P2, m, 64);
            P3 += __shfl_xor(P3, m, 64);
        }

        const bool t0 = ((double)u0 >= P0);
        const bool t1 = ((double)u1 >= P1);
        const bool t2 = ((double)u2 >= P2);
        const bool t3 = ((double)u3 >= P3);
        const double s0 = t0 ? (1.0 - P0) : P0;   // p0+p1==1 by isometry
        const double s1 = t1 ? (1.0 - P1) : P1;
        const double s2 = t2 ? (1.0 - P2) : P2;
        const double s3 = t3 ? (1.0 - P3) : P3;
        const double i0 = rsqrt(s0);              // ~1 ulp; perturbs L ~1e-15 rel
        const double i1 = rsqrt(s1);
        const double i2 = rsqrt(s2);
        const double i3 = rsqrt(s3);

        // chosen T -> new L rows at probed (row,col); strip-private (no barrier)
        double* LwB = Lsm + (16 * w) * LPAD;
        LwB[row0 * LPAD +  0 + col0] = (t0 ? c4.x : c0.x) * i0;
        LwB[row0 * LPAD + 16 + col0] = (t0 ? c5.x : c1.x) * i0;
        LwB[row0 * LPAD + 32 + col0] = (t0 ? c6.x : c2.x) * i0;
        LwB[row0 * LPAD + 48 + col0] = (t0 ? c7.x : c3.x) * i0;
        LwB[row1 * LPAD +  0 + col1] = (t1 ? c4.y : c0.y) * i1;
        LwB[row1 * LPAD + 16 + col1] = (t1 ? c5.y : c1.y) * i1;
        LwB[row1 * LPAD + 32 + col1] = (t1 ? c6.y : c2.y) * i1;
        LwB[row1 * LPAD + 48 + col1] = (t1 ? c7.y : c3.y) * i1;
        LwB[row2 * LPAD +  0 + col2] = (t2 ? c4.z : c0.z) * i2;
        LwB[row2 * LPAD + 16 + col2] = (t2 ? c5.z : c1.z) * i2;
        LwB[row2 * LPAD + 32 + col2] = (t2 ? c6.z : c2.z) * i2;
        LwB[row2 * LPAD + 48 + col2] = (t2 ? c7.z : c3.z) * i2;
        LwB[row3 * LPAD +  0 + col3] = (t3 ? c4.w : c0.w) * i3;
        LwB[row3 * LPAD + 16 + col3] = (t3 ? c5.w : c1.w) * i3;
        LwB[row3 * LPAD + 32 + col3] = (t3 ? c6.w : c2.w) * i3;
        LwB[row3 * LPAD + 48 + col3] = (t3 ? c7.w : c3.w) * i3;

        if (r == 0) {   // rows {row0..row3} per g partition 0..15 -> full cover
            probOut[(size_t)(ubase + row0) * NSITES + site] = (float)s0;
            probOut[(size_t)(ubase + row1) * NSITES + site] = (float)s1;
            probOut[(size_t)(ubase + row2) * NSITES + site] = (float)s2;
            probOut[(size_t)(ubase + row3) * NSITES + site] = (float)s3;
            *(float2*)(out + (size_t)(ubase + row0) * 128 + site * 2) = make_float2(t0 ? 1.f : 0.f, t0 ? 0.f : 1.f);
            *(float2*)(out + (size_t)(ubase + row1) * 128 + site * 2) = make_float2(t1 ? 1.f : 0.f, t1 ? 0.f : 1.f);
            *(float2*)(out + (size_t)(ubase + row2) * 128 + site * 2) = make_float2(t2 ? 1.f : 0.f, t2 ? 0.f : 1.f);
            *(float2*)(out + (size_t)(ubase + row3) * 128 + site * 2) = make_float2(t3 ? 1.f : 0.f, t3 ? 0.f : 1.f);
        }

        __syncthreads();                 // BAR_B: all H1 reads done; H0 staged

        // write H1 (overlaps next site's u-loads/glb-issue/H0 MFMAs)
        if (site < NSITES - 1) {
            double2* a2 = (double2*)As;
            a2[4 * 512 + tid] = st4; a2[5 * 512 + tid] = st5;
            a2[6 * 512 + tid] = st6; a2[7 * 512 + tid] = st7;
        }
    }
}

extern "C" void kernel_launch(void* const* d_in, const int* in_sizes, int n_in,
                              void* d_out, int out_size, void* d_ws, size_t ws_size,
                              hipStream_t stream)
{
    const float* W = (const float*)d_in[0];   // [64,64,2,64] f32
    const float* u = (const float*)d_in[1];   // [32768,64] f32
    float* out = (float*)d_out;               // s_hat [B,64,2] then prob [B,64]
    double* A8 = (double*)d_ws;               // isometrized A, f64, 4 MiB

    hipLaunchKernelGGL(qr_site_kernel, dim3(NSITES), dim3(512), 0, stream, W, A8);
    hipLaunchKernelGGL(sample_kernel, dim3(256), dim3(512), 0, stream, A8, u, out);
}

// Round 12
// 818.534 us; speedup vs baseline: 1.1301x; 1.1301x over previous
//
#include <hip/hip_runtime.h>

#define NSITES 64
#define CHI 64
#define BATCH 32768
#define LPAD 66          // L row stride in doubles

typedef double d4 __attribute__((ext_vector_type(4)));

// 32 cycles of guaranteed spacing between MFMA result writes and VALU reads,
// pinned so the compiler cannot move register-only MFMAs across (rule #18).
#define MFMA_HAZARD_FENCE() do {                                    \
    __builtin_amdgcn_sched_barrier(0);                              \
    asm volatile("s_nop 7\n\ts_nop 7\n\ts_nop 7\n\ts_nop 7" :::);   \
    __builtin_amdgcn_sched_barrier(0);                              \
} while (0)

// ============================================================================
// Kernel 1: per-site Householder QR (LAPACK dgeqrf/dorgqr convention), f64.
// REVERTED to the rounds-3..10 version (round-11 "optimized" QR regressed
// ~147 -> ~272 us: divergent fused-norm path + serial scalar chain).
// A output bit-identical to all passing rounds.
// ============================================================================
__global__ __launch_bounds__(512) void qr_site_kernel(
    const float* __restrict__ W, double* __restrict__ A8)
{
    __shared__ double M[128][65];
    __shared__ double wpart[8][64];
    __shared__ double tauS[64];
    __shared__ double redS[2];
    __shared__ double vcol[136];

    const int i   = blockIdx.x;
    const int tid = threadIdx.x;

    for (int idx = tid; idx < 8192; idx += 512) {
        int l = idx >> 7, sr = idx & 127;
        M[sr][l] = (double)W[i * 8192 + idx];
    }
    __syncthreads();

    const int jf = tid & 63;
    const int gf = tid >> 6;
    const int r0 = gf * 16;

    for (int k = 0; k < 64; ++k) {
        const double alpha = M[k][k];
        double v2 = 0.0;
        if (tid < 128) { double xv = (tid > k) ? M[tid][k] : 0.0; v2 = xv * xv; }
        #pragma unroll
        for (int off = 32; off; off >>= 1) v2 += __shfl_down(v2, off, 64);
        if (tid < 128 && (tid & 63) == 0) redS[tid >> 6] = v2;
        __syncthreads();
        const double xnorm2 = redS[0] + redS[1];

        double beta, tk;
        if (xnorm2 == 0.0) { beta = alpha; tk = 0.0; }
        else {
            double nrm = sqrt(alpha * alpha + xnorm2);
            beta = (alpha >= 0.0) ? -nrm : nrm;
            tk   = (beta - alpha) / beta;
        }
        const double sc = (tk != 0.0) ? (1.0 / (alpha - beta)) : 0.0;
        if (tid < 128 && tid > k && tk != 0.0) M[tid][k] *= sc;
        if (tid == 0) tauS[k] = tk;
        __syncthreads();

        double part = 0.0;
        if (jf > k) {
            #pragma unroll 4
            for (int m = 0; m < 16; ++m) {
                int rr = r0 + m;
                double vr = (rr > k) ? M[rr][k] : ((rr == k) ? 1.0 : 0.0);
                part = fma(vr, M[rr][jf], part);
            }
        }
        wpart[gf][jf] = part;
        __syncthreads();
        if (jf > k) {
            double wj = tauS[k] * (wpart[0][jf] + wpart[1][jf] + wpart[2][jf] + wpart[3][jf]
                                 + wpart[4][jf] + wpart[5][jf] + wpart[6][jf] + wpart[7][jf]);
            #pragma unroll 4
            for (int m = 0; m < 16; ++m) {
                int rr = r0 + m;
                double vr = (rr > k) ? M[rr][k] : ((rr == k) ? 1.0 : 0.0);
                M[rr][jf] = fma(-vr, wj, M[rr][jf]);
            }
        }
        __syncthreads();
    }

    const int jq = tid >> 3;
    const int qq = tid & 7;
    double E[16];
    #pragma unroll
    for (int m = 0; m < 16; ++m) E[m] = ((qq * 16 + m) == jq) ? 1.0 : 0.0;

    for (int k = 63; k >= 0; --k) {
        if (tid < 128) {
            double val = (tid > k) ? M[tid][k] : ((tid == k) ? 1.0 : 0.0);
            vcol[tid + (tid >> 4)] = val;
        }
        __syncthreads();
        const double tkk = tauS[k];
        double part = 0.0;
        #pragma unroll
        for (int m = 0; m < 16; ++m) {
            int rr = qq * 16 + m;
            part = fma(vcol[rr + qq], E[m], part);
        }
        part += __shfl_xor(part, 1, 64);
        part += __shfl_xor(part, 2, 64);
        part += __shfl_xor(part, 4, 64);
        const double wj = tkk * part;
        #pragma unroll
        for (int m = 0; m < 16; ++m) {
            int rr = qq * 16 + m;
            E[m] = fma(-vcol[rr + qq], wj, E[m]);
        }
        __syncthreads();
    }

    double* dst = A8 + (size_t)i * 8192 + jq * 128 + qq * 16;
    #pragma unroll
    for (int m = 0; m < 16; ++m) dst[m] = E[m];
}

// ============================================================================
// Kernel 2: sampling via f64 MFMA GEMM. CHANGE vs round 11: TWO independent
// 256-thread blocks per CU (grid 512, 64 batches/block). Quarter-tile
// ping-pong staging (As0/As1 = 16 rows each), ONE 4-wave barrier per quarter:
//   q: { ds_write pend -> other buf; issue loads 2 quarters ahead; MFMA 32x } BAR
// Epilogue is strip-private; while one block runs it, the co-resident block
// keeps the SIMD MFMA pipe fed (round-11 MfmaUtil 73.8% -> target ~90%).
// Per-wave FMA order (kk 0..15) bit-identical to rounds 7-11.
// LDS/block = 32 KiB As + 33 KiB Lsm = 65 KiB -> exactly 2 blocks/CU.
// ============================================================================
#define MFMA_ROW(bp, a)                                                   \
    c0 = __builtin_amdgcn_mfma_f64_16x16x4f64((a), (bp)[  0], c0, 0,0,0); \
    c1 = __builtin_amdgcn_mfma_f64_16x16x4f64((a), (bp)[ 16], c1, 0,0,0); \
    c2 = __builtin_amdgcn_mfma_f64_16x16x4f64((a), (bp)[ 32], c2, 0,0,0); \
    c3 = __builtin_amdgcn_mfma_f64_16x16x4f64((a), (bp)[ 48], c3, 0,0,0); \
    c4 = __builtin_amdgcn_mfma_f64_16x16x4f64((a), (bp)[ 64], c4, 0,0,0); \
    c5 = __builtin_amdgcn_mfma_f64_16x16x4f64((a), (bp)[ 80], c5, 0,0,0); \
    c6 = __builtin_amdgcn_mfma_f64_16x16x4f64((a), (bp)[ 96], c6, 0,0,0); \
    c7 = __builtin_amdgcn_mfma_f64_16x16x4f64((a), (bp)[112], c7, 0,0,0);

// one quarter: 4 K-steps on buffer BUF with L-column base QB
#define MFMA_QUARTER(BUF, QB) do {                                        \
    const double* bq = (BUF) + g * 128 + r;                               \
    { const double a = Lp[(QB) +  0]; MFMA_ROW(bq +    0, a) }            \
    { const double a = Lp[(QB) +  4]; MFMA_ROW(bq +  512, a) }            \
    { const double a = Lp[(QB) +  8]; MFMA_ROW(bq + 1024, a) }            \
    { const double a = Lp[(QB) + 12]; MFMA_ROW(bq + 1536, a) }            \
} while (0)

#define STAGE_WRITE(BUF, S0, S1, S2, S3) do {                             \
    double2* b2 = (double2*)(BUF);                                        \
    b2[0 * 256 + tid] = S0; b2[1 * 256 + tid] = S1;                       \
    b2[2 * 256 + tid] = S2; b2[3 * 256 + tid] = S3;                       \
} while (0)

#define STAGE_LOAD(D, S0, S1, S2, S3) do {                                \
    const double2* nx2 = (const double2*)(A8 + (size_t)(D) * 2048);       \
    S0 = nx2[0 * 256 + tid]; S1 = nx2[1 * 256 + tid];                     \
    S2 = nx2[2 * 256 + tid]; S3 = nx2[3 * 256 + tid];                     \
} while (0)

__global__ __launch_bounds__(256, 2) void sample_kernel(
    const double* __restrict__ A8, const float* __restrict__ u,
    float* __restrict__ out)
{
    __shared__ __align__(16) double As0[2048];       // quarter buf: [16][128]
    __shared__ __align__(16) double As1[2048];
    __shared__ double Lsm[64 * LPAD];                // L: [b=64][66]

    const int tid  = threadIdx.x;
    const int w    = tid >> 6;            // wave 0..3
    const int lane = tid & 63;
    const int g    = lane >> 4;           // 0..3
    const int r    = lane & 15;           // 0..15
    const int ubase = blockIdx.x * 64 + 16 * w;    // strip's first global batch

    // ---- layout probe (register-only, once) ----
    d4 zp = {0.0, 0.0, 0.0, 0.0};
    const d4 rowP = __builtin_amdgcn_mfma_f64_16x16x4f64((g == 0) ? (double)r : 0.0, 1.0, zp, 0, 0, 0);
    const d4 colP = __builtin_amdgcn_mfma_f64_16x16x4f64((g == 0) ? 1.0 : 0.0, (double)r, zp, 0, 0, 0);
    MFMA_HAZARD_FENCE();
    const int row0 = (int)(rowP.x + 0.5), row1 = (int)(rowP.y + 0.5);
    const int row2 = (int)(rowP.z + 0.5), row3 = (int)(rowP.w + 0.5);
    const int col0 = (int)(colP.x + 0.5), col1 = (int)(colP.y + 0.5);
    const int col2 = (int)(colP.z + 0.5), col3 = (int)(colP.w + 0.5);

    // init L = e_0: lane (g,r) initializes row 16w+r, cols g, g+4, ...
    for (int j = g; j < 64; j += 4)
        Lsm[(16 * w + r) * LPAD + j] = (j == 0) ? 1.0 : 0.0;

    // prologue: quarter 0 -> As0; quarter 1 -> regs (sA)
    double2 sA0, sA1, sA2, sA3, sB0, sB1, sB2, sB3;
    STAGE_LOAD(0, sA0, sA1, sA2, sA3);
    STAGE_WRITE(As0, sA0, sA1, sA2, sA3);
    STAGE_LOAD(1, sA0, sA1, sA2, sA3);
    __syncthreads();

    float* probOut = out + (size_t)BATCH * (NSITES * 2);

    for (int site = 0; site < NSITES; ++site) {
        const int d = site * 4;
        // u values for this lane's (probed) batch rows
        const float u0 = u[(size_t)(ubase + row0) * NSITES + site];
        const float u1 = u[(size_t)(ubase + row1) * NSITES + site];
        const float u2 = u[(size_t)(ubase + row2) * NSITES + site];
        const float u3 = u[(size_t)(ubase + row3) * NSITES + site];

        d4 c0 = {0.0, 0.0, 0.0, 0.0}, c1 = c0, c2 = c0, c3 = c0;
        d4 c4 = c0, c5 = c0, c6 = c0, c7 = c0;
        const double* Lp = Lsm + (16 * w + r) * LPAD + g;

        // ---- q0: MFMA As0 (=d+0) | write sA(d+1)->As1 | load sB=d+2 ----
        STAGE_WRITE(As1, sA0, sA1, sA2, sA3);
        STAGE_LOAD(d + 2, sB0, sB1, sB2, sB3);
        MFMA_QUARTER(As0, 0);
        __syncthreads();

        // ---- q1: MFMA As1 (=d+1) | write sB(d+2)->As0 | load sA=d+3 ----
        STAGE_WRITE(As0, sB0, sB1, sB2, sB3);
        STAGE_LOAD(d + 3, sA0, sA1, sA2, sA3);
        MFMA_QUARTER(As1, 16);
        __syncthreads();

        // ---- q2: MFMA As0 (=d+2) | write sA(d+3)->As1 | load sB=d+4 ----
        STAGE_WRITE(As1, sA0, sA1, sA2, sA3);
        if (site < NSITES - 1) STAGE_LOAD(d + 4, sB0, sB1, sB2, sB3);
        MFMA_QUARTER(As0, 32);
        __syncthreads();

        // ---- q3: MFMA As1 (=d+3) | write sB(d+4)->As0 | load sA=d+5 ----
        if (site < NSITES - 1) {
            STAGE_WRITE(As0, sB0, sB1, sB2, sB3);
            STAGE_LOAD(d + 5, sA0, sA1, sA2, sA3);
        }
        MFMA_QUARTER(As1, 48);
        MFMA_HAZARD_FENCE();             // settle c-reg writes before VALU reads

        // ---- epilogue (strip-private; no cross-wave deps) ----
        double P0 = fma(c3.x, c3.x, fma(c2.x, c2.x, fma(c1.x, c1.x, c0.x * c0.x)));
        double P1 = fma(c3.y, c3.y, fma(c2.y, c2.y, fma(c1.y, c1.y, c0.y * c0.y)));
        double P2 = fma(c3.z, c3.z, fma(c2.z, c2.z, fma(c1.z, c1.z, c0.z * c0.z)));
        double P3 = fma(c3.w, c3.w, fma(c2.w, c2.w, fma(c1.w, c1.w, c0.w * c0.w)));
        #pragma unroll
        for (int m = 1; m <= 8; m <<= 1) {
            P0 += __shfl_xor(P0, m, 64);
            P1 += __shfl_xor(P1, m, 64);
            P2 += __shfl_xor(P2, m, 64);
            P3 += __shfl_xor(P3, m, 64);
        }

        const bool t0 = ((double)u0 >= P0);
        const bool t1 = ((double)u1 >= P1);
        const bool t2 = ((double)u2 >= P2);
        const bool t3 = ((double)u3 >= P3);
        const double s0 = t0 ? (1.0 - P0) : P0;   // p0+p1==1 by isometry
        const double s1 = t1 ? (1.0 - P1) : P1;
        const double s2 = t2 ? (1.0 - P2) : P2;
        const double s3 = t3 ? (1.0 - P3) : P3;
        const double i0 = rsqrt(s0);
        const double i1 = rsqrt(s1);
        const double i2 = rsqrt(s2);
        const double i3 = rsqrt(s3);

        double* LwB = Lsm + (16 * w) * LPAD;
        LwB[row0 * LPAD +  0 + col0] = (t0 ? c4.x : c0.x) * i0;
        LwB[row0 * LPAD + 16 + col0] = (t0 ? c5.x : c1.x) * i0;
        LwB[row0 * LPAD + 32 + col0] = (t0 ? c6.x : c2.x) * i0;
        LwB[row0 * LPAD + 48 + col0] = (t0 ? c7.x : c3.x) * i0;
        LwB[row1 * LPAD +  0 + col1] = (t1 ? c4.y : c0.y) * i1;
        LwB[row1 * LPAD + 16 + col1] = (t1 ? c5.y : c1.y) * i1;
        LwB[row1 * LPAD + 32 + col1] = (t1 ? c6.y : c2.y) * i1;
        LwB[row1 * LPAD + 48 + col1] = (t1 ? c7.y : c3.y) * i1;
        LwB[row2 * LPAD +  0 + col2] = (t2 ? c4.z : c0.z) * i2;
        LwB[row2 * LPAD + 16 + col2] = (t2 ? c5.z : c1.z) * i2;
        LwB[row2 * LPAD + 32 + col2] = (t2 ? c6.z : c2.z) * i2;
        LwB[row2 * LPAD + 48 + col2] = (t2 ? c7.z : c3.z) * i2;
        LwB[row3 * LPAD +  0 + col3] = (t3 ? c4.w : c0.w) * i3;
        LwB[row3 * LPAD + 16 + col3] = (t3 ? c5.w : c1.w) * i3;
        LwB[row3 * LPAD + 32 + col3] = (t3 ? c6.w : c2.w) * i3;
        LwB[row3 * LPAD + 48 + col3] = (t3 ? c7.w : c3.w) * i3;

        if (r == 0) {
            probOut[(size_t)(ubase + row0) * NSITES + site] = (float)s0;
            probOut[(size_t)(ubase + row1) * NSITES + site] = (float)s1;
            probOut[(size_t)(ubase + row2) * NSITES + site] = (float)s2;
            probOut[(size_t)(ubase + row3) * NSITES + site] = (float)s3;
            *(float2*)(out + (size_t)(ubase + row0) * 128 + site * 2) = make_float2(t0 ? 1.f : 0.f, t0 ? 0.f : 1.f);
            *(float2*)(out + (size_t)(ubase + row1) * 128 + site * 2) = make_float2(t1 ? 1.f : 0.f, t1 ? 0.f : 1.f);
            *(float2*)(out + (size_t)(ubase + row2) * 128 + site * 2) = make_float2(t2 ? 1.f : 0.f, t2 ? 0.f : 1.f);
            *(float2*)(out + (size_t)(ubase + row3) * 128 + site * 2) = make_float2(t3 ? 1.f : 0.f, t3 ? 0.f : 1.f);
        }

        __syncthreads();                 // end of q3 phase: As1 reads done
    }
}

extern "C" void kernel_launch(void* const* d_in, const int* in_sizes, int n_in,
                              void* d_out, int out_size, void* d_ws, size_t ws_size,
                              hipStream_t stream)
{
    const float* W = (const float*)d_in[0];   // [64,64,2,64] f32
    const float* u = (const float*)d_in[1];   // [32768,64] f32
    float* out = (float*)d_out;               // s_hat [B,64,2] then prob [B,64]
    double* A8 = (double*)d_ws;               // isometrized A, f64, 4 MiB

    hipLaunchKernelGGL(qr_site_kernel, dim3(NSITES), dim3(512), 0, stream, W, A8);
    hipLaunchKernelGGL(sample_kernel, dim3(512), dim3(256), 0, stream, A8, u, out);
}

// Round 13
// 803.019 us; speedup vs baseline: 1.1519x; 1.0193x over previous
//
#include <hip/hip_runtime.h>

#define NSITES 64
#define CHI 64
#define BATCH 32768
#define LPAD 66          // L row stride in doubles

typedef double d4 __attribute__((ext_vector_type(4)));

// 32 cycles of guaranteed spacing between MFMA result writes and VALU reads,
// pinned so the compiler cannot move register-only MFMAs across (rule #18).
#define MFMA_HAZARD_FENCE() do {                                    \
    __builtin_amdgcn_sched_barrier(0);                              \
    asm volatile("s_nop 7\n\ts_nop 7\n\ts_nop 7\n\ts_nop 7" :::);   \
    __builtin_amdgcn_sched_barrier(0);                              \
} while (0)

// ============================================================================
// Kernel 1: per-site Householder QR (LAPACK dgeqrf/dorgqr convention), f64.
// Factor phase: UNCHANGED from rounds 3-10/12 (passing; A bit-identical).
// Q-phase: one-time transpose of scaled v's into padded Vt[64][136]
// (idx rr+(rr>>4): conflict-free octant reads, 8-way broadcast), then 64
// iterations with ZERO barriers (Vt/tauS read-only). Removes 128 barriers.
// ============================================================================
__global__ __launch_bounds__(512) void qr_site_kernel(
    const float* __restrict__ W, double* __restrict__ A8)
{
    __shared__ double M[128][65];
    __shared__ double wpart[8][64];
    __shared__ double tauS[64];
    __shared__ double redS[2];
    __shared__ double Vt[64][136];

    const int i   = blockIdx.x;
    const int tid = threadIdx.x;

    for (int idx = tid; idx < 8192; idx += 512) {
        int l = idx >> 7, sr = idx & 127;
        M[sr][l] = (double)W[i * 8192 + idx];
    }
    __syncthreads();

    const int jf = tid & 63;
    const int gf = tid >> 6;
    const int r0 = gf * 16;

    for (int k = 0; k < 64; ++k) {
        const double alpha = M[k][k];
        double v2 = 0.0;
        if (tid < 128) { double xv = (tid > k) ? M[tid][k] : 0.0; v2 = xv * xv; }
        #pragma unroll
        for (int off = 32; off; off >>= 1) v2 += __shfl_down(v2, off, 64);
        if (tid < 128 && (tid & 63) == 0) redS[tid >> 6] = v2;
        __syncthreads();
        const double xnorm2 = redS[0] + redS[1];

        double beta, tk;
        if (xnorm2 == 0.0) { beta = alpha; tk = 0.0; }
        else {
            double nrm = sqrt(alpha * alpha + xnorm2);
            beta = (alpha >= 0.0) ? -nrm : nrm;
            tk   = (beta - alpha) / beta;
        }
        const double sc = (tk != 0.0) ? (1.0 / (alpha - beta)) : 0.0;
        if (tid < 128 && tid > k && tk != 0.0) M[tid][k] *= sc;
        if (tid == 0) tauS[k] = tk;
        __syncthreads();

        double part = 0.0;
        if (jf > k) {
            #pragma unroll 4
            for (int m = 0; m < 16; ++m) {
                int rr = r0 + m;
                double vr = (rr > k) ? M[rr][k] : ((rr == k) ? 1.0 : 0.0);
                part = fma(vr, M[rr][jf], part);
            }
        }
        wpart[gf][jf] = part;
        __syncthreads();
        if (jf > k) {
            double wj = tauS[k] * (wpart[0][jf] + wpart[1][jf] + wpart[2][jf] + wpart[3][jf]
                                 + wpart[4][jf] + wpart[5][jf] + wpart[6][jf] + wpart[7][jf]);
            #pragma unroll 4
            for (int m = 0; m < 16; ++m) {
                int rr = r0 + m;
                double vr = (rr > k) ? M[rr][k] : ((rr == k) ? 1.0 : 0.0);
                M[rr][jf] = fma(-vr, wj, M[rr][jf]);
            }
        }
        __syncthreads();
    }

    // one-time transpose of scaled v's (v_k = 1 explicit) into Vt
    for (int idx = tid; idx < 8192; idx += 512) {
        int rr = idx & 127, k = idx >> 7;
        double val = (rr > k) ? M[rr][k] : ((rr == k) ? 1.0 : 0.0);
        Vt[k][rr + (rr >> 4)] = val;
    }
    __syncthreads();

    // Q = H_0 ... H_63 applied to [I;0], reverse order — ZERO barriers
    const int jq = tid >> 3;
    const int qq = tid & 7;
    double E[16];
    #pragma unroll
    for (int m = 0; m < 16; ++m) E[m] = ((qq * 16 + m) == jq) ? 1.0 : 0.0;

    for (int k = 63; k >= 0; --k) {
        const double tkk = tauS[k];
        double part = 0.0;
        #pragma unroll
        for (int m = 0; m < 16; ++m) {
            int rr = qq * 16 + m;
            part = fma(Vt[k][rr + qq], E[m], part);
        }
        part += __shfl_xor(part, 1, 64);
        part += __shfl_xor(part, 2, 64);
        part += __shfl_xor(part, 4, 64);
        const double wj = tkk * part;
        #pragma unroll
        for (int m = 0; m < 16; ++m) {
            int rr = qq * 16 + m;
            E[m] = fma(-Vt[k][rr + qq], wj, E[m]);
        }
    }

    double* dst = A8 + (size_t)i * 8192 + jq * 128 + qq * 16;
    #pragma unroll
    for (int m = 0; m < 16; ++m) dst[m] = E[m];
}

// ============================================================================
// Kernel 2: sampling via f64 MFMA GEMM per site — ROUND-11 version verbatim
// (best measured: 653 us, MfmaUtil 73.8%, replay-stable). Zero-serial staging:
//   issue nxH0 | MFMA kk0..7 (H0) | BAR_A | ds_write H0 + issue nxH1 |
//   MFMA kk8..15 (H1) | fence | epilogue+L+outputs | BAR_B | ds_write H1
// ============================================================================
#define MFMA_ROW(bp, a)                                                   \
    c0 = __builtin_amdgcn_mfma_f64_16x16x4f64((a), (bp)[  0], c0, 0,0,0); \
    c1 = __builtin_amdgcn_mfma_f64_16x16x4f64((a), (bp)[ 16], c1, 0,0,0); \
    c2 = __builtin_amdgcn_mfma_f64_16x16x4f64((a), (bp)[ 32], c2, 0,0,0); \
    c3 = __builtin_amdgcn_mfma_f64_16x16x4f64((a), (bp)[ 48], c3, 0,0,0); \
    c4 = __builtin_amdgcn_mfma_f64_16x16x4f64((a), (bp)[ 64], c4, 0,0,0); \
    c5 = __builtin_amdgcn_mfma_f64_16x16x4f64((a), (bp)[ 80], c5, 0,0,0); \
    c6 = __builtin_amdgcn_mfma_f64_16x16x4f64((a), (bp)[ 96], c6, 0,0,0); \
    c7 = __builtin_amdgcn_mfma_f64_16x16x4f64((a), (bp)[112], c7, 0,0,0);

__global__ __launch_bounds__(512, 2) void sample_kernel(
    const double* __restrict__ A8, const float* __restrict__ u,
    float* __restrict__ out)
{
    __shared__ __align__(16) double As[8192];        // A_i: [j=64][sr=128], 64 KiB
    __shared__ double Lsm[128 * LPAD];               // L: [b=128][j=64 + pad], 66 KiB

    const int tid  = threadIdx.x;
    const int w    = tid >> 6;            // wave 0..7
    const int lane = tid & 63;
    const int g    = lane >> 4;           // 0..3
    const int r    = lane & 15;           // 0..15
    const int ubase = blockIdx.x * 128 + 16 * w;   // strip's first global batch

    // ---- layout probe (register-only, once) ----
    d4 zp = {0.0, 0.0, 0.0, 0.0};
    const d4 rowP = __builtin_amdgcn_mfma_f64_16x16x4f64((g == 0) ? (double)r : 0.0, 1.0, zp, 0, 0, 0);
    const d4 colP = __builtin_amdgcn_mfma_f64_16x16x4f64((g == 0) ? 1.0 : 0.0, (double)r, zp, 0, 0, 0);
    MFMA_HAZARD_FENCE();
    const int row0 = (int)(rowP.x + 0.5), row1 = (int)(rowP.y + 0.5);
    const int row2 = (int)(rowP.z + 0.5), row3 = (int)(rowP.w + 0.5);
    const int col0 = (int)(colP.x + 0.5), col1 = (int)(colP.y + 0.5);
    const int col2 = (int)(colP.z + 0.5), col3 = (int)(colP.w + 0.5);

    // init L = e_0: lane (g,r) initializes row 16w+r, cols g, g+4, ...
    for (int j = g; j < 64; j += 4)
        Lsm[(16 * w + r) * LPAD + j] = (j == 0) ? 1.0 : 0.0;

    {   // stage site 0 (full)
        const double2* s2 = (const double2*)A8;
        double2* a2 = (double2*)As;
        #pragma unroll
        for (int q = 0; q < 8; ++q) a2[q * 512 + tid] = s2[q * 512 + tid];
    }
    __syncthreads();

    float* probOut = out + (size_t)BATCH * (NSITES * 2);

    for (int site = 0; site < NSITES; ++site) {
        // u values for this lane's (probed) batch rows
        const float u0 = u[(size_t)(ubase + row0) * NSITES + site];
        const float u1 = u[(size_t)(ubase + row1) * NSITES + site];
        const float u2 = u[(size_t)(ubase + row2) * NSITES + site];
        const float u3 = u[(size_t)(ubase + row3) * NSITES + site];

        // issue next-site H0 loads (arrive under first MFMA half)
        double2 st0, st1, st2, st3;
        if (site < NSITES - 1) {
            const double2* nx = (const double2*)(A8 + (size_t)(site + 1) * 8192);
            st0 = nx[0 * 512 + tid]; st1 = nx[1 * 512 + tid];
            st2 = nx[2 * 512 + tid]; st3 = nx[3 * 512 + tid];
        }

        d4 c0 = {0.0, 0.0, 0.0, 0.0}, c1 = c0, c2 = c0, c3 = c0;
        d4 c4 = c0, c5 = c0, c6 = c0, c7 = c0;

        const double* Lp = Lsm + (16 * w + r) * LPAD + g;   // A-op: L[16w+r][g+4kk]
        const double* Ap = As + g * 128 + r;                // B-op: A[g+4kk][16t+r]

        // ---- first half: kk 0..7 (reads As rows 0..31 = H0) ----
        #pragma unroll
        for (int kk = 0; kk < 8; ++kk) {
            const double a = Lp[4 * kk];
            const double* bp = Ap + kk * 512;
            MFMA_ROW(bp, a)
        }

        __syncthreads();                 // BAR_A: all H0 reads done

        // overwrite H0 + issue H1 loads; both overlap the second MFMA half
        double2 st4, st5, st6, st7;
        if (site < NSITES - 1) {
            double2* a2 = (double2*)As;
            a2[0 * 512 + tid] = st0; a2[1 * 512 + tid] = st1;
            a2[2 * 512 + tid] = st2; a2[3 * 512 + tid] = st3;
            const double2* nx = (const double2*)(A8 + (size_t)(site + 1) * 8192);
            st4 = nx[4 * 512 + tid]; st5 = nx[5 * 512 + tid];
            st6 = nx[6 * 512 + tid]; st7 = nx[7 * 512 + tid];
        }

        // ---- second half: kk 8..15 (reads As rows 32..63 = H1) ----
        #pragma unroll
        for (int kk = 8; kk < 16; ++kk) {
            const double a = Lp[4 * kk];
            const double* bp = Ap + kk * 512;
            MFMA_ROW(bp, a)
        }
        MFMA_HAZARD_FENCE();             // settle all c-reg writes before VALU reads

        // p0 per row: tiles 0..3 are the s=0 half (col-permutation-invariant);
        // xor-butterfly over the 16-lane group (row map is r-independent).
        double P0 = fma(c3.x, c3.x, fma(c2.x, c2.x, fma(c1.x, c1.x, c0.x * c0.x)));
        double P1 = fma(c3.y, c3.y, fma(c2.y, c2.y, fma(c1.y, c1.y, c0.y * c0.y)));
        double P2 = fma(c3.z, c3.z, fma(c2.z, c2.z, fma(c1.z, c1.z, c0.z * c0.z)));
        double P3 = fma(c3.w, c3.w, fma(c2.w, c2.w, fma(c1.w, c1.w, c0.w * c0.w)));
        #pragma unroll
        for (int m = 1; m <= 8; m <<= 1) {
            P0 += __shfl_xor(P0, m, 64);
            P1 += __shfl_xor(P1, m, 64);
            P2 += __shfl_xor(P2, m, 64);
            P3 += __shfl_xor(P3, m, 64);
        }

        const bool t0 = ((double)u0 >= P0);
        const bool t1 = ((double)u1 >= P1);
        const bool t2 = ((double)u2 >= P2);
        const bool t3 = ((double)u3 >= P3);
        const double s0 = t0 ? (1.0 - P0) : P0;   // p0+p1==1 by isometry
        const double s1 = t1 ? (1.0 - P1) : P1;
        const double s2 = t2 ? (1.0 - P2) : P2;
        const double s3 = t3 ? (1.0 - P3) : P3;
        const double i0 = rsqrt(s0);              // ~1 ulp; perturbs L ~1e-15 rel
        const double i1 = rsqrt(s1);
        const double i2 = rsqrt(s2);
        const double i3 = rsqrt(s3);

        // chosen T -> new L rows at probed (row,col); strip-private (no barrier)
        double* LwB = Lsm + (16 * w) * LPAD;
        LwB[row0 * LPAD +  0 + col0] = (t0 ? c4.x : c0.x) * i0;
        LwB[row0 * LPAD + 16 + col0] = (t0 ? c5.x : c1.x) * i0;
        LwB[row0 * LPAD + 32 + col0] = (t0 ? c6.x : c2.x) * i0;
        LwB[row0 * LPAD + 48 + col0] = (t0 ? c7.x : c3.x) * i0;
        LwB[row1 * LPAD +  0 + col1] = (t1 ? c4.y : c0.y) * i1;
        LwB[row1 * LPAD + 16 + col1] = (t1 ? c5.y : c1.y) * i1;
        LwB[row1 * LPAD + 32 + col1] = (t1 ? c6.y : c2.y) * i1;
        LwB[row1 * LPAD + 48 + col1] = (t1 ? c7.y : c3.y) * i1;
        LwB[row2 * LPAD +  0 + col2] = (t2 ? c4.z : c0.z) * i2;
        LwB[row2 * LPAD + 16 + col2] = (t2 ? c5.z : c1.z) * i2;
        LwB[row2 * LPAD + 32 + col2] = (t2 ? c6.z : c2.z) * i2;
        LwB[row2 * LPAD + 48 + col2] = (t2 ? c7.z : c3.z) * i2;
        LwB[row3 * LPAD +  0 + col3] = (t3 ? c4.w : c0.w) * i3;
        LwB[row3 * LPAD + 16 + col3] = (t3 ? c5.w : c1.w) * i3;
        LwB[row3 * LPAD + 32 + col3] = (t3 ? c6.w : c2.w) * i3;
        LwB[row3 * LPAD + 48 + col3] = (t3 ? c7.w : c3.w) * i3;

        if (r == 0) {   // rows {row0..row3} per g partition 0..15 -> full cover
            probOut[(size_t)(ubase + row0) * NSITES + site] = (float)s0;
            probOut[(size_t)(ubase + row1) * NSITES + site] = (float)s1;
            probOut[(size_t)(ubase + row2) * NSITES + site] = (float)s2;
            probOut[(size_t)(ubase + row3) * NSITES + site] = (float)s3;
            *(float2*)(out + (size_t)(ubase + row0) * 128 + site * 2) = make_float2(t0 ? 1.f : 0.f, t0 ? 0.f : 1.f);
            *(float2*)(out + (size_t)(ubase + row1) * 128 + site * 2) = make_float2(t1 ? 1.f : 0.f, t1 ? 0.f : 1.f);
            *(float2*)(out + (size_t)(ubase + row2) * 128 + site * 2) = make_float2(t2 ? 1.f : 0.f, t2 ? 0.f : 1.f);
            *(float2*)(out + (size_t)(ubase + row3) * 128 + site * 2) = make_float2(t3 ? 1.f : 0.f, t3 ? 0.f : 1.f);
        }

        __syncthreads();                 // BAR_B: all H1 reads done; H0 staged

        // write H1 (overlaps next site's u-loads/glb-issue/H0 MFMAs)
        if (site < NSITES - 1) {
            double2* a2 = (double2*)As;
            a2[4 * 512 + tid] = st4; a2[5 * 512 + tid] = st5;
            a2[6 * 512 + tid] = st6; a2[7 * 512 + tid] = st7;
        }
    }
}

extern "C" void kernel_launch(void* const* d_in, const int* in_sizes, int n_in,
                              void* d_out, int out_size, void* d_ws, size_t ws_size,
                              hipStream_t stream)
{
    const float* W = (const float*)d_in[0];   // [64,64,2,64] f32
    const float* u = (const float*)d_in[1];   // [32768,64] f32
    float* out = (float*)d_out;               // s_hat [B,64,2] then prob [B,64]
    double* A8 = (double*)d_ws;               // isometrized A, f64, 4 MiB

    hipLaunchKernelGGL(qr_site_kernel, dim3(NSITES), dim3(512), 0, stream, W, A8);
    hipLaunchKernelGGL(sample_kernel, dim3(256), dim3(512), 0, stream, A8, u, out);
}

// Round 14
// 751.863 us; speedup vs baseline: 1.2303x; 1.0680x over previous
//
#include <hip/hip_runtime.h>

#define NSITES 64
#define CHI 64
#define BATCH 32768
#define LPAD 66          // L row stride in doubles

typedef double d4 __attribute__((ext_vector_type(4)));

// 32 cycles of guaranteed spacing between MFMA result writes and VALU reads,
// pinned so the compiler cannot move register-only MFMAs across (rule #18).
#define MFMA_HAZARD_FENCE() do {                                    \
    __builtin_amdgcn_sched_barrier(0);                              \
    asm volatile("s_nop 7\n\ts_nop 7\n\ts_nop 7\n\ts_nop 7" :::);   \
    __builtin_amdgcn_sched_barrier(0);                              \
} while (0)

// ============================================================================
// Kernel 1: per-site Householder QR (LAPACK dgeqrf/dorgqr convention), f64.
// Factor phase REWRITTEN to 2 barriers/iter, divergence-free:
//   A: ureg[16] <- col k (wave-broadcast); group norm partial computed
//      redundantly by ALL lanes (no lane-specialized branch); GEMV on the
//      UNSCALED column -> wpart.
//   B: scalars; wj = (tau/uk^2)*(uk*x_k + sum wpart)  [== old wj/uk, so
//      update M -= ureg*wj is the old Householder update to the ulp];
//      rows<=k have ureg=0 (same-value writes, benign). Col-k scaling is
//      DEFERRED: scS[k] stored, applied in the Vt transpose (bit-identical
//      product to the old in-place scale).
// Q-phase: one-time transpose into padded Vt[64][136], zero barriers (r13).
// Norm regrouping perturbs the gauge ~1 ulp (decision-flip prob ~4e-8).
// ============================================================================
__global__ __launch_bounds__(512) void qr_site_kernel(
    const float* __restrict__ W, double* __restrict__ A8)
{
    __shared__ double M[128][65];
    __shared__ double wpart[8][64];
    __shared__ double tauS[64];
    __shared__ double scS[64];
    __shared__ double redS2[8];
    __shared__ double Vt[64][136];

    const int i   = blockIdx.x;
    const int tid = threadIdx.x;

    for (int idx = tid; idx < 8192; idx += 512) {
        int l = idx >> 7, sr = idx & 127;
        M[sr][l] = (double)W[i * 8192 + idx];
    }

    const int jf = tid & 63;              // lane = column
    const int gf = tid >> 6;              // wave = row group (rows gf*16..+15)
    const int r0 = gf * 16;
    __syncthreads();

    for (int k = 0; k < 64; ++k) {
        // ---- phase A ----
        double ureg[16];
        #pragma unroll
        for (int m = 0; m < 16; ++m) {
            int rr = r0 + m;
            ureg[m] = (rr > k) ? M[rr][k] : 0.0;   // wave-broadcast reads
        }
        double np = 0.0;                  // group norm partial (all lanes, uniform)
        #pragma unroll
        for (int m = 0; m < 16; ++m) np = fma(ureg[m], ureg[m], np);
        if (jf == 0) redS2[gf] = np;
        if (jf > k) {                     // GEMV on unscaled column
            double part = 0.0;
            #pragma unroll 4
            for (int m = 0; m < 16; ++m)
                part = fma(ureg[m], M[r0 + m][jf], part);
            wpart[gf][jf] = part;
        }
        __syncthreads();                  // barrier 1

        // ---- phase B ----
        const double v2 = ((redS2[0] + redS2[1]) + (redS2[2] + redS2[3]))
                        + ((redS2[4] + redS2[5]) + (redS2[6] + redS2[7]));
        const double alpha = M[k][k];
        double beta, tk;
        if (v2 == 0.0) { beta = alpha; tk = 0.0; }
        else {
            double nrm = sqrt(alpha * alpha + v2);
            beta = (alpha >= 0.0) ? -nrm : nrm;   // LAPACK sign convention
            tk   = (beta - alpha) / beta;
        }
        const double uk   = alpha - beta;
        const double sc   = (tk != 0.0) ? (1.0 / uk) : 0.0;
        const double tau2 = (tk != 0.0) ? (tk / (uk * uk)) : 0.0;
        if (tid == 0) { tauS[k] = tk; scS[k] = sc; }
        if (jf > k) {
            const double xk = M[k][jf];   // row-k term (col k never scaled here)
            double wsum = ((wpart[0][jf] + wpart[1][jf]) + (wpart[2][jf] + wpart[3][jf]))
                        + ((wpart[4][jf] + wpart[5][jf]) + (wpart[6][jf] + wpart[7][jf]));
            const double wj = tau2 * fma(uk, xk, wsum);
            #pragma unroll 4
            for (int m = 0; m < 16; ++m) {
                int rr = r0 + m;
                M[rr][jf] = fma(-ureg[m], wj, M[rr][jf]);  // rows<=k: -0*wj, benign
            }
        }
        __syncthreads();                  // barrier 2
    }

    // one-time transpose of v's into Vt, applying the deferred scale
    // (M[rr][k]*scS[k] is the SAME product the old code computed in place)
    for (int idx = tid; idx < 8192; idx += 512) {
        int rr = idx & 127, k = idx >> 7;
        double val = (rr > k) ? M[rr][k] * scS[k] : ((rr == k) ? 1.0 : 0.0);
        Vt[k][rr + (rr >> 4)] = val;
    }
    __syncthreads();

    // Q = H_0 ... H_63 applied to [I;0], reverse order — ZERO barriers
    const int jq = tid >> 3;
    const int qq = tid & 7;
    double E[16];
    #pragma unroll
    for (int m = 0; m < 16; ++m) E[m] = ((qq * 16 + m) == jq) ? 1.0 : 0.0;

    for (int k = 63; k >= 0; --k) {
        const double tkk = tauS[k];
        double part = 0.0;
        #pragma unroll
        for (int m = 0; m < 16; ++m) {
            int rr = qq * 16 + m;
            part = fma(Vt[k][rr + qq], E[m], part);
        }
        part += __shfl_xor(part, 1, 64);
        part += __shfl_xor(part, 2, 64);
        part += __shfl_xor(part, 4, 64);
        const double wj = tkk * part;
        #pragma unroll
        for (int m = 0; m < 16; ++m) {
            int rr = qq * 16 + m;
            E[m] = fma(-Vt[k][rr + qq], wj, E[m]);
        }
    }

    double* dst = A8 + (size_t)i * 8192 + jq * 128 + qq * 16;
    #pragma unroll
    for (int m = 0; m < 16; ++m) dst[m] = E[m];
}

// ============================================================================
// Kernel 2: sampling via f64 MFMA GEMM per site — ROUND-13 version VERBATIM
// (652 us, MfmaUtil 73.8%, replay-stable). Zero-serial staging schedule.
// ============================================================================
#define MFMA_ROW(bp, a)                                                   \
    c0 = __builtin_amdgcn_mfma_f64_16x16x4f64((a), (bp)[  0], c0, 0,0,0); \
    c1 = __builtin_amdgcn_mfma_f64_16x16x4f64((a), (bp)[ 16], c1, 0,0,0); \
    c2 = __builtin_amdgcn_mfma_f64_16x16x4f64((a), (bp)[ 32], c2, 0,0,0); \
    c3 = __builtin_amdgcn_mfma_f64_16x16x4f64((a), (bp)[ 48], c3, 0,0,0); \
    c4 = __builtin_amdgcn_mfma_f64_16x16x4f64((a), (bp)[ 64], c4, 0,0,0); \
    c5 = __builtin_amdgcn_mfma_f64_16x16x4f64((a), (bp)[ 80], c5, 0,0,0); \
    c6 = __builtin_amdgcn_mfma_f64_16x16x4f64((a), (bp)[ 96], c6, 0,0,0); \
    c7 = __builtin_amdgcn_mfma_f64_16x16x4f64((a), (bp)[112], c7, 0,0,0);

__global__ __launch_bounds__(512, 2) void sample_kernel(
    const double* __restrict__ A8, const float* __restrict__ u,
    float* __restrict__ out)
{
    __shared__ __align__(16) double As[8192];        // A_i: [j=64][sr=128], 64 KiB
    __shared__ double Lsm[128 * LPAD];               // L: [b=128][j=64 + pad], 66 KiB

    const int tid  = threadIdx.x;
    const int w    = tid >> 6;            // wave 0..7
    const int lane = tid & 63;
    const int g    = lane >> 4;           // 0..3
    const int r    = lane & 15;           // 0..15
    const int ubase = blockIdx.x * 128 + 16 * w;   // strip's first global batch

    // ---- layout probe (register-only, once) ----
    d4 zp = {0.0, 0.0, 0.0, 0.0};
    const d4 rowP = __builtin_amdgcn_mfma_f64_16x16x4f64((g == 0) ? (double)r : 0.0, 1.0, zp, 0, 0, 0);
    const d4 colP = __builtin_amdgcn_mfma_f64_16x16x4f64((g == 0) ? 1.0 : 0.0, (double)r, zp, 0, 0, 0);
    MFMA_HAZARD_FENCE();
    const int row0 = (int)(rowP.x + 0.5), row1 = (int)(rowP.y + 0.5);
    const int row2 = (int)(rowP.z + 0.5), row3 = (int)(rowP.w + 0.5);
    const int col0 = (int)(colP.x + 0.5), col1 = (int)(colP.y + 0.5);
    const int col2 = (int)(colP.z + 0.5), col3 = (int)(colP.w + 0.5);

    // init L = e_0: lane (g,r) initializes row 16w+r, cols g, g+4, ...
    for (int j = g; j < 64; j += 4)
        Lsm[(16 * w + r) * LPAD + j] = (j == 0) ? 1.0 : 0.0;

    {   // stage site 0 (full)
        const double2* s2 = (const double2*)A8;
        double2* a2 = (double2*)As;
        #pragma unroll
        for (int q = 0; q < 8; ++q) a2[q * 512 + tid] = s2[q * 512 + tid];
    }
    __syncthreads();

    float* probOut = out + (size_t)BATCH * (NSITES * 2);

    for (int site = 0; site < NSITES; ++site) {
        // u values for this lane's (probed) batch rows
        const float u0 = u[(size_t)(ubase + row0) * NSITES + site];
        const float u1 = u[(size_t)(ubase + row1) * NSITES + site];
        const float u2 = u[(size_t)(ubase + row2) * NSITES + site];
        const float u3 = u[(size_t)(ubase + row3) * NSITES + site];

        // issue next-site H0 loads (arrive under first MFMA half)
        double2 st0, st1, st2, st3;
        if (site < NSITES - 1) {
            const double2* nx = (const double2*)(A8 + (size_t)(site + 1) * 8192);
            st0 = nx[0 * 512 + tid]; st1 = nx[1 * 512 + tid];
            st2 = nx[2 * 512 + tid]; st3 = nx[3 * 512 + tid];
        }

        d4 c0 = {0.0, 0.0, 0.0, 0.0}, c1 = c0, c2 = c0, c3 = c0;
        d4 c4 = c0, c5 = c0, c6 = c0, c7 = c0;

        const double* Lp = Lsm + (16 * w + r) * LPAD + g;   // A-op: L[16w+r][g+4kk]
        const double* Ap = As + g * 128 + r;                // B-op: A[g+4kk][16t+r]

        // ---- first half: kk 0..7 (reads As rows 0..31 = H0) ----
        #pragma unroll
        for (int kk = 0; kk < 8; ++kk) {
            const double a = Lp[4 * kk];
            const double* bp = Ap + kk * 512;
            MFMA_ROW(bp, a)
        }

        __syncthreads();                 // BAR_A: all H0 reads done

        // overwrite H0 + issue H1 loads; both overlap the second MFMA half
        double2 st4, st5, st6, st7;
        if (site < NSITES - 1) {
            double2* a2 = (double2*)As;
            a2[0 * 512 + tid] = st0; a2[1 * 512 + tid] = st1;
            a2[2 * 512 + tid] = st2; a2[3 * 512 + tid] = st3;
            const double2* nx = (const double2*)(A8 + (size_t)(site + 1) * 8192);
            st4 = nx[4 * 512 + tid]; st5 = nx[5 * 512 + tid];
            st6 = nx[6 * 512 + tid]; st7 = nx[7 * 512 + tid];
        }

        // ---- second half: kk 8..15 (reads As rows 32..63 = H1) ----
        #pragma unroll
        for (int kk = 8; kk < 16; ++kk) {
            const double a = Lp[4 * kk];
            const double* bp = Ap + kk * 512;
            MFMA_ROW(bp, a)
        }
        MFMA_HAZARD_FENCE();             // settle all c-reg writes before VALU reads

        // p0 per row: tiles 0..3 are the s=0 half (col-permutation-invariant);
        // xor-butterfly over the 16-lane group (row map is r-independent).
        double P0 = fma(c3.x, c3.x, fma(c2.x, c2.x, fma(c1.x, c1.x, c0.x * c0.x)));
        double P1 = fma(c3.y, c3.y, fma(c2.y, c2.y, fma(c1.y, c1.y, c0.y * c0.y)));
        double P2 = fma(c3.z, c3.z, fma(c2.z, c2.z, fma(c1.z, c1.z, c0.z * c0.z)));
        double P3 = fma(c3.w, c3.w, fma(c2.w, c2.w, fma(c1.w, c1.w, c0.w * c0.w)));
        #pragma unroll
        for (int m = 1; m <= 8; m <<= 1) {
            P0 += __shfl_xor(P0, m, 64);
            P1 += __shfl_xor(P1, m, 64);
            P2 += __shfl_xor(P2, m, 64);
            P3 += __shfl_xor(P3, m, 64);
        }

        const bool t0 = ((double)u0 >= P0);
        const bool t1 = ((double)u1 >= P1);
        const bool t2 = ((double)u2 >= P2);
        const bool t3 = ((double)u3 >= P3);
        const double s0 = t0 ? (1.0 - P0) : P0;   // p0+p1==1 by isometry
        const double s1 = t1 ? (1.0 - P1) : P1;
        const double s2 = t2 ? (1.0 - P2) : P2;
        const double s3 = t3 ? (1.0 - P3) : P3;
        const double i0 = rsqrt(s0);              // ~1 ulp; perturbs L ~1e-15 rel
        const double i1 = rsqrt(s1);
        const double i2 = rsqrt(s2);
        const double i3 = rsqrt(s3);

        // chosen T -> new L rows at probed (row,col); strip-private (no barrier)
        double* LwB = Lsm + (16 * w) * LPAD;
        LwB[row0 * LPAD +  0 + col0] = (t0 ? c4.x : c0.x) * i0;
        LwB[row0 * LPAD + 16 + col0] = (t0 ? c5.x : c1.x) * i0;
        LwB[row0 * LPAD + 32 + col0] = (t0 ? c6.x : c2.x) * i0;
        LwB[row0 * LPAD + 48 + col0] = (t0 ? c7.x : c3.x) * i0;
        LwB[row1 * LPAD +  0 + col1] = (t1 ? c4.y : c0.y) * i1;
        LwB[row1 * LPAD + 16 + col1] = (t1 ? c5.y : c1.y) * i1;
        LwB[row1 * LPAD + 32 + col1] = (t1 ? c6.y : c2.y) * i1;
        LwB[row1 * LPAD + 48 + col1] = (t1 ? c7.y : c3.y) * i1;
        LwB[row2 * LPAD +  0 + col2] = (t2 ? c4.z : c0.z) * i2;
        LwB[row2 * LPAD + 16 + col2] = (t2 ? c5.z : c1.z) * i2;
        LwB[row2 * LPAD + 32 + col2] = (t2 ? c6.z : c2.z) * i2;
        LwB[row2 * LPAD + 48 + col2] = (t2 ? c7.z : c3.z) * i2;
        LwB[row3 * LPAD +  0 + col3] = (t3 ? c4.w : c0.w) * i3;
        LwB[row3 * LPAD + 16 + col3] = (t3 ? c5.w : c1.w) * i3;
        LwB[row3 * LPAD + 32 + col3] = (t3 ? c6.w : c2.w) * i3;
        LwB[row3 * LPAD + 48 + col3] = (t3 ? c7.w : c3.w) * i3;

        if (r == 0) {   // rows {row0..row3} per g partition 0..15 -> full cover
            probOut[(size_t)(ubase + row0) * NSITES + site] = (float)s0;
            probOut[(size_t)(ubase + row1) * NSITES + site] = (float)s1;
            probOut[(size_t)(ubase + row2) * NSITES + site] = (float)s2;
            probOut[(size_t)(ubase + row3) * NSITES + site] = (float)s3;
            *(float2*)(out + (size_t)(ubase + row0) * 128 + site * 2) = make_float2(t0 ? 1.f : 0.f, t0 ? 0.f : 1.f);
            *(float2*)(out + (size_t)(ubase + row1) * 128 + site * 2) = make_float2(t1 ? 1.f : 0.f, t1 ? 0.f : 1.f);
            *(float2*)(out + (size_t)(ubase + row2) * 128 + site * 2) = make_float2(t2 ? 1.f : 0.f, t2 ? 0.f : 1.f);
            *(float2*)(out + (size_t)(ubase + row3) * 128 + site * 2) = make_float2(t3 ? 1.f : 0.f, t3 ? 0.f : 1.f);
        }

        __syncthreads();                 // BAR_B: all H1 reads done; H0 staged

        // write H1 (overlaps next site's u-loads/glb-issue/H0 MFMAs)
        if (site < NSITES - 1) {
            double2* a2 = (double2*)As;
            a2[4 * 512 + tid] = st4; a2[5 * 512 + tid] = st5;
            a2[6 * 512 + tid] = st6; a2[7 * 512 + tid] = st7;
        }
    }
}

extern "C" void kernel_launch(void* const* d_in, const int* in_sizes, int n_in,
                              void* d_out, int out_size, void* d_ws, size_t ws_size,
                              hipStream_t stream)
{
    const float* W = (const float*)d_in[0];   // [64,64,2,64] f32
    const float* u = (const float*)d_in[1];   // [32768,64] f32
    float* out = (float*)d_out;               // s_hat [B,64,2] then prob [B,64]
    double* A8 = (double*)d_ws;               // isometrized A, f64, 4 MiB

    hipLaunchKernelGGL(qr_site_kernel, dim3(NSITES), dim3(512), 0, stream, W, A8);
    hipLaunchKernelGGL(sample_kernel, dim3(256), dim3(512), 0, stream, A8, u, out);
}